// Round 5
// baseline (441.057 us; speedup 1.0000x reference)
//
#include <hip/hip_runtime.h>
#include <cstdint>
#include <cstddef>

typedef __attribute__((ext_vector_type(8))) _Float16 f16x8;
typedef __attribute__((ext_vector_type(4))) float f32x4;
typedef __attribute__((ext_vector_type(8))) short bf16x8;
typedef __attribute__((ext_vector_type(8))) unsigned short ushort8;

// flag margin for fp16 2-term (err_diff 10-sigma ~ 3e-3) + key-quantization slack
#define MARGIN2F 4.5e-3f

__device__ __forceinline__ unsigned short f2bf(float f) {
  union { float f; unsigned int u; } x; x.f = f;
  unsigned int r = (x.u + 0x7fffu + ((x.u >> 16) & 1u)) >> 16;  // RNE
  return (unsigned short)r;
}
__device__ __forceinline__ unsigned short f2h(float f) {
  union { _Float16 h; unsigned short u; } c; c.h = (_Float16)f; return c.u;
}
__device__ __forceinline__ float h2f(unsigned short u) {
  union { unsigned short u; _Float16 h; } c; c.u = u; return (float)c.h;
}
// monotone float -> sortable u32 ordinal
__device__ __forceinline__ unsigned int f2ord(float v) {
  unsigned int s = __float_as_uint(v);
  return s ^ ((unsigned int)((int)s >> 31) | 0x80000000u);
}
__device__ __forceinline__ float ord2f(unsigned int o) {
  unsigned int s = (o & 0x80000000u) ? (o ^ 0x80000000u) : ~o;
  return __uint_as_float(s);
}

// ---------------------------------------------------------------------------
// kprep: fused {zero Mt, W3->bf16, W1->hi/lo fp16, const[k]=W3[k,:]·b2+b3[k]}
// ---------------------------------------------------------------------------
__global__ __launch_bounds__(256) void kprep(
    float* __restrict__ Mt,
    const float* __restrict__ W3, unsigned short* __restrict__ W3b,
    const float* __restrict__ W1, unsigned short* __restrict__ w1h,
    unsigned short* __restrict__ w1l,
    const float* __restrict__ b2, const float* __restrict__ b3,
    float* __restrict__ constv) {
  __shared__ float red[4];
  const int bid = blockIdx.x;
  const int t = threadIdx.x;
  if (bid < 512) {
    int e = bid * 256 + t;  // 2 MB of zeros
    ((float4*)Mt)[e] = (float4){0.f, 0.f, 0.f, 0.f};
  } else if (bid < 768) {
    int e = ((bid - 512) * 256 + t) * 8;  // W3 -> bf16
    float4 f0 = *(const float4*)(W3 + e);
    float4 f1 = *(const float4*)(W3 + e + 4);
    ushort8 v;
    v[0] = f2bf(f0.x); v[1] = f2bf(f0.y); v[2] = f2bf(f0.z); v[3] = f2bf(f0.w);
    v[4] = f2bf(f1.x); v[5] = f2bf(f1.y); v[6] = f2bf(f1.z); v[7] = f2bf(f1.w);
    *(ushort8*)(W3b + e) = v;
  } else if (bid < 1024) {
    int e = ((bid - 768) * 256 + t) * 8;  // W1 -> hi/lo fp16
    float ff[8];
    *(float4*)&ff[0] = *(const float4*)(W1 + e);
    *(float4*)&ff[4] = *(const float4*)(W1 + e + 4);
    ushort8 h, l;
#pragma unroll
    for (int i = 0; i < 8; i++) {
      unsigned short hi = f2h(ff[i]);
      h[i] = hi;
      l[i] = f2h(ff[i] - h2f(hi));
    }
    *(ushort8*)(w1h + e) = h;
    *(ushort8*)(w1l + e) = l;
  } else {
    int k = bid - 1024;  // const[k]
    float s = 0.f;
    for (int j = t; j < 4096; j += 256) s += W3[k * 4096 + j] * b2[j];
#pragma unroll
    for (int mk = 1; mk < 64; mk <<= 1) s += __shfl_xor(s, mk, 64);
    if ((t & 63) == 0) red[t >> 6] = s;
    __syncthreads();
    if (t == 0) constv[k] = red[0] + red[1] + red[2] + red[3] + b3[k];
  }
}

// ---------------------------------------------------------------------------
// K1 v5: fp16 2-term (W1 split hi/lo fp16, x rounded once to fp16) +
// block-local exact fixup (k1_fix fused in, one launch fewer).
//   Structure = round-4 proven: 512 blocks x 512 thr (8 waves), swapped
//   operands (A=W1, B=x), 4 waves/SIMD. MFMA per (a,b): 2-deep chain
//   mfma(wh,xh)+mfma(wl,xh) (was 3-deep) -> -33% instr, -1/3 chain latency.
//   x staged fp16 ONLY (xsh, 17.4 KB; no xsl) -> LDS reads & conflicts halve.
// Numerics: logit err = sum xl*w (x fp16-rounding only), sigma~1.7e-4,
//   realistic max ~1.2e-3. Flag if quantized-key gap < 4.5e-3 (>10-sigma on
//   the pairwise err difference + 4.8e-4 key slack). Flagged (row,seg) are
//   recomputed EXACTLY (fp32, ascending-k fmaf, identical to the proven
//   k1_fix) in-block after the seg loop. Flags are block-local by design;
//   LDS list capacity 1024 = max possible -> no overflow path.
// ---------------------------------------------------------------------------
__global__ __launch_bounds__(512, 4) void k1_mfma(
    const float* __restrict__ x, const unsigned short* __restrict__ w1h,
    const unsigned short* __restrict__ w1l, const float* __restrict__ b1,
    const float* __restrict__ W1, int* __restrict__ idxbuf) {
  __shared__ unsigned short xsh[64 * 136];   // fp16 x tile, stride 136
  __shared__ uint2 wavebuf[8 * 64];          // [wave][row] sorted key pair
  __shared__ unsigned short flags[1024];     // block-local (row<<4|seg)
  __shared__ int flagn;
  __shared__ float redv[4];
  __shared__ int   redi[4];

  const int t = threadIdx.x;
  const int r0 = blockIdx.x * 64;
  if (t == 0) flagn = 0;

  // ---- stage x rows 64x128 -> fp16 (once per block) ----
#pragma unroll
  for (int it = 0; it < 2; it++) {
    int ch = it * 512 + t;          // 1024 chunks of 8 elems
    int row = ch >> 4, k8 = ch & 15;
    float ff[8];
    *(float4*)&ff[0] = *(const float4*)(x + (r0 + row) * 128 + k8 * 8);
    *(float4*)&ff[4] = *(const float4*)(x + (r0 + row) * 128 + k8 * 8 + 4);
    ushort8 h;
#pragma unroll
    for (int i = 0; i < 8; i++) h[i] = f2h(ff[i]);
    *(ushort8*)&xsh[row * 136 + k8 * 8] = h;
  }
  __syncthreads();

  const int lane = t & 63, w = t >> 6;      // 8 waves
  const int m = lane & 15, q = lane >> 4;

  for (int seg = 0; seg < 16; ++seg) {
    const int cb = seg * 256 + w * 32;      // wave's first seg-col

    f32x4 acc[2][4];
#pragma unroll
    for (int a = 0; a < 2; a++)
#pragma unroll
      for (int b = 0; b < 4; b++) acc[a][b] = (f32x4){0.f, 0.f, 0.f, 0.f};

#pragma unroll
    for (int ks = 0; ks < 4; ks++) {
      const int k0 = ks * 32;
      // A-frags: W1 hi/lo fp16 rows cb+a*16+m (global, L2-resident)
      f16x8 ah[2], al[2];
#pragma unroll
      for (int a = 0; a < 2; a++) {
        const size_t woff = (size_t)(cb + a * 16 + m) * 128 + k0 + q * 8;
        ah[a] = *(const f16x8*)(w1h + woff);
        al[a] = *(const f16x8*)(w1l + woff);
      }
      // B-frags: x rows (fp16, hi only) from LDS
#pragma unroll
      for (int bp = 0; bp < 2; bp++) {
        f16x8 bx[2];
#pragma unroll
        for (int bb = 0; bb < 2; bb++) {
          const int roff = ((bp * 2 + bb) * 16 + m) * 136 + k0 + q * 8;
          bx[bb] = *(const f16x8*)&xsh[roff];
        }
#pragma unroll
        for (int a = 0; a < 2; a++)
#pragma unroll
          for (int bb = 0; bb < 2; bb++) {
            const int b = bp * 2 + bb;
            acc[a][b] = __builtin_amdgcn_mfma_f32_16x16x32_f16(ah[a], bx[bb], acc[a][b], 0, 0, 0);
            acc[a][b] = __builtin_amdgcn_mfma_f32_16x16x32_f16(al[a], bx[bb], acc[a][b], 0, 0, 0);
          }
      }
    }

    // ---- epilogue: per-row top-2 keys (round-4 proven) ----
    float4 bias4[2];
#pragma unroll
    for (int a = 0; a < 2; a++)
      bias4[a] = *(const float4*)&b1[cb + a * 16 + q * 4];

#pragma unroll
    for (int b = 0; b < 4; b++) {
      unsigned int K1 = 0u, K2 = 0u;
#pragma unroll
      for (int a = 0; a < 2; a++)
#pragma unroll
        for (int r = 0; r < 4; r++) {
          float v = acc[a][b][r] + bias4[a][r];
          unsigned int col = (unsigned)(w * 32 + a * 16 + q * 4 + r);
          unsigned int key = (f2ord(v) & 0xFFFFFF00u) | (255u - col);
          unsigned int mx = K1 > key ? K1 : key;
          unsigned int mn = K1 > key ? key : K1;
          K1 = mx; K2 = K2 > mn ? K2 : mn;
        }
#pragma unroll
      for (int msk = 16; msk <= 32; msk <<= 1) {
        unsigned int p1 = (unsigned int)__shfl_xor((int)K1, msk, 64);
        unsigned int p2 = (unsigned int)__shfl_xor((int)K2, msk, 64);
        unsigned int mx = K1 > p1 ? K1 : p1;
        unsigned int mn = K1 > p1 ? p1 : K1;
        unsigned int sel = K1 >= p1 ? K2 : p2;
        K1 = mx;
        K2 = sel > mn ? sel : mn;
      }
      if (lane < 16) {  // q == 0
        uint2 pr; pr.x = K1; pr.y = K2;
        wavebuf[w * 64 + b * 16 + m] = pr;
      }
    }
    __syncthreads();

    // ---- merge 8 wave pairs per row; emit idx + local near-tie flag ----
    if (t < 64) {
      unsigned int K1 = 0u, K2 = 0u;
#pragma unroll
      for (int wp = 0; wp < 8; wp++) {
        uint2 pr = wavebuf[wp * 64 + t];
        unsigned int mx = K1 > pr.x ? K1 : pr.x;
        unsigned int mn = K1 > pr.x ? pr.x : K1;
        unsigned int sel = K1 >= pr.x ? K2 : pr.y;
        K1 = mx;
        K2 = sel > mn ? sel : mn;
      }
      int colw = 255 - (int)(K1 & 255u);
      idxbuf[(r0 + t) * 16 + seg] = colw;
      float v1 = ord2f(K1 & 0xFFFFFF00u);
      float v2 = ord2f(K2 & 0xFFFFFF00u);
      if (v1 - v2 < MARGIN2F) {
        int p = atomicAdd(&flagn, 1);        // LDS atomic
        flags[p] = (unsigned short)((t << 4) | seg);
      }
    }
    __syncthreads();  // protect wavebuf + flags before next seg
  }

  // ---- block-local exact fixup (numerics identical to proven k1_fix) ----
  const int n = flagn;
  for (int e = 0; e < n; e++) {
    int pk = flags[e];
    int row = r0 + (pk >> 4), seg = pk & 15;
    if (t < 256) {
      int c = seg * 256 + t;
      float a = b1[c];
      const float4* xr = (const float4*)(x + (size_t)row * 128);
      const float4* wr = (const float4*)(W1 + (size_t)c * 128);
#pragma unroll 8
      for (int k4 = 0; k4 < 32; k4++) {
        float4 xv = xr[k4];
        float4 wv4 = wr[k4];
        a = fmaf(xv.x, wv4.x, a);
        a = fmaf(xv.y, wv4.y, a);
        a = fmaf(xv.z, wv4.z, a);
        a = fmaf(xv.w, wv4.w, a);
      }
      float v = a; int li = t;
#pragma unroll
      for (int msk = 1; msk < 64; msk <<= 1) {
        float u = __shfl_xor(v, msk, 64);
        int ju = __shfl_xor(li, msk, 64);
        if (u > v || (u == v && ju < li)) { v = u; li = ju; }
      }
      if (lane == 0) { redv[w] = v; redi[w] = li; }
    }
    __syncthreads();
    if (t == 0) {
      float bv = redv[0]; int bi = redi[0];
#pragma unroll
      for (int wp = 1; wp < 4; wp++) {
        if (redv[wp] > bv || (redv[wp] == bv && redi[wp] < bi)) { bv = redv[wp]; bi = redi[wp]; }
      }
      idxbuf[row * 16 + seg] = bi;
    }
    __syncthreads();
  }
}

// ---------------------------------------------------------------------------
// K2: Mt[c,k] += sum_j W2[j,c]*W3[k,j], splitK=8, LDS-transposed staging
// (round-4 version, unchanged).
// ---------------------------------------------------------------------------
__global__ __launch_bounds__(256) void k2_mfma(const float* __restrict__ W2,
                                               const unsigned short* __restrict__ W3b,
                                               float* __restrict__ Mt) {
  __shared__ unsigned short ldsT[64 * 40];
  const int t = threadIdx.x;
  const int lane = t & 63, wv = t >> 6;
  const int c0 = blockIdx.x * 64;
  const int jq = blockIdx.y;
  const int m = lane & 15, q = lane >> 4;
  f32x4 acc[8];
#pragma unroll
  for (int nt = 0; nt < 8; nt++) acc[nt] = (f32x4){0.f, 0.f, 0.f, 0.f};

  for (int it = 0; it < 16; it++) {
    const int j0 = jq * 512 + it * 32;
#pragma unroll
    for (int i = 0; i < 2; i++) {
      int fid = i * 256 + t;
      int jl = fid >> 4, cq = fid & 15;
      float4 v = *(const float4*)&W2[(size_t)(j0 + jl) * 4096 + c0 + cq * 4];
      ldsT[(cq * 4 + 0) * 40 + jl] = f2bf(v.x);
      ldsT[(cq * 4 + 1) * 40 + jl] = f2bf(v.y);
      ldsT[(cq * 4 + 2) * 40 + jl] = f2bf(v.z);
      ldsT[(cq * 4 + 3) * 40 + jl] = f2bf(v.w);
    }
    __syncthreads();
    bf16x8 av = *(const bf16x8*)&ldsT[(wv * 16 + m) * 40 + q * 8];
#pragma unroll
    for (int nt = 0; nt < 8; nt++) {
      bf16x8 b = *(const bf16x8*)(W3b + (nt * 16 + m) * 4096 + j0 + q * 8);
      acc[nt] = __builtin_amdgcn_mfma_f32_16x16x32_bf16(av, b, acc[nt], 0, 0, 0);
    }
    __syncthreads();
  }
#pragma unroll
  for (int nt = 0; nt < 8; nt++)
#pragma unroll
    for (int r = 0; r < 4; r++)
      atomicAdd(&Mt[(size_t)(c0 + wv * 16 + q * 4 + r) * 128 + nt * 16 + m], acc[nt][r]);
}

// ---------------------------------------------------------------------------
// K3: out[b,k] = const[k] + sum_g Mt[g*256 + idx[b,g], k]  (unchanged)
// ---------------------------------------------------------------------------
__global__ __launch_bounds__(256) void k3_gather(const int* __restrict__ idxbuf,
                                                 const float* __restrict__ Mt,
                                                 const float* __restrict__ constv,
                                                 float* __restrict__ out) {
  const int t = threadIdx.x;
  const int w = t >> 6;
  const int lane = t & 63;
  const int b = blockIdx.x * 4 + w;
  float a0 = constv[lane];
  float a1 = constv[lane + 64];
  const int* ib = idxbuf + b * 16;
  int cg[16];
#pragma unroll
  for (int g = 0; g < 16; g++) cg[g] = g * 256 + ib[g];
#pragma unroll
  for (int g = 0; g < 16; g++) {
    const float* mrow = Mt + (size_t)cg[g] * 128;
    a0 += mrow[lane];
    a1 += mrow[lane + 64];
  }
  out[b * 128 + lane] = a0;
  out[b * 128 + lane + 64] = a1;
}

// ---------------------------------------------------------------------------
extern "C" void kernel_launch(void* const* d_in, const int* in_sizes, int n_in,
                              void* d_out, int out_size, void* d_ws, size_t ws_size,
                              hipStream_t stream) {
  const float* x  = (const float*)d_in[0];
  const float* W1 = (const float*)d_in[1];
  const float* b1 = (const float*)d_in[2];
  const float* W2 = (const float*)d_in[3];
  const float* b2 = (const float*)d_in[4];
  const float* W3 = (const float*)d_in[5];
  const float* b3 = (const float*)d_in[6];
  float* out = (float*)d_out;

  char* w = (char*)d_ws;
  int* idxbuf         = (int*)(w);                           // 2 MB
  unsigned short* W3b = (unsigned short*)(w + (2u << 20));   // 1 MB
  float* Mt           = (float*)(w + (3u << 20));            // 2 MB
  unsigned short* w1h = (unsigned short*)(w + (5u << 20));   // 1 MB (fp16 hi)
  unsigned short* w1l = (unsigned short*)(w + (6u << 20));   // 1 MB (fp16 lo)
  float* constv       = (float*)(w + (7u << 20));            // 512 B

  kprep<<<1152, 256, 0, stream>>>(Mt, W3, W3b, W1, w1h, w1l, b2, b3, constv);
  k1_mfma<<<512, 512, 0, stream>>>(x, w1h, w1l, b1, W1, idxbuf);
  k2_mfma<<<dim3(64, 8), 256, 0, stream>>>(W2, W3b, Mt);
  k3_gather<<<8192, 256, 0, stream>>>(idxbuf, Mt, constv, out);
}

// Round 7
// 343.974 us; speedup vs baseline: 1.2822x; 1.2822x over previous
//
#include <hip/hip_runtime.h>
#include <cstdint>
#include <cstddef>

typedef __attribute__((ext_vector_type(8))) short bf16x8;
typedef __attribute__((ext_vector_type(4))) float f32x4;
typedef __attribute__((ext_vector_type(8))) unsigned short ushort8;

#define FIX_CAP 65536
// quantized-key flag margin: proven 1e-3 + 2*2.4e-4 key-truncation slack (rounds 1/3/4 verified)
#define MARGIN2 1.5e-3f

__device__ __forceinline__ unsigned short f2bf(float f) {
  union { float f; unsigned int u; } x; x.f = f;
  unsigned int r = (x.u + 0x7fffu + ((x.u >> 16) & 1u)) >> 16;  // RNE
  return (unsigned short)r;
}
__device__ __forceinline__ float bf2f(unsigned short h) {
  union { unsigned int u; float f; } x; x.u = ((unsigned int)h) << 16;
  return x.f;
}
// monotone float -> sortable u32 ordinal
__device__ __forceinline__ unsigned int f2ord(float v) {
  unsigned int s = __float_as_uint(v);
  return s ^ ((unsigned int)((int)s >> 31) | 0x80000000u);
}
__device__ __forceinline__ float ord2f(unsigned int o) {
  unsigned int s = (o & 0x80000000u) ? (o ^ 0x80000000u) : ~o;
  return __uint_as_float(s);
}

// lgkm-only barrier: drains LDS ops but leaves global loads in flight
// (vs __syncthreads(), which the compiler fronts with s_waitcnt vmcnt(0)).
__device__ __forceinline__ void barrier_lgkm() {
  asm volatile("s_waitcnt lgkmcnt(0)" ::: "memory");
  __builtin_amdgcn_s_barrier();
}

// ---------------------------------------------------------------------------
// kprep: fused {zero Mt + cnt, W3->bf16, W1->hi/lo bf16, const[k]=W3[k,:]·b2+b3[k]}
// ---------------------------------------------------------------------------
__global__ __launch_bounds__(256) void kprep(
    float* __restrict__ Mt, int* __restrict__ cnt,
    const float* __restrict__ W3, unsigned short* __restrict__ W3b,
    const float* __restrict__ W1, unsigned short* __restrict__ w1h,
    unsigned short* __restrict__ w1l,
    const float* __restrict__ b2, const float* __restrict__ b3,
    float* __restrict__ constv) {
  __shared__ float red[4];
  const int bid = blockIdx.x;
  const int t = threadIdx.x;
  if (bid < 512) {
    int e = bid * 256 + t;  // 2 MB of zeros
    ((float4*)Mt)[e] = (float4){0.f, 0.f, 0.f, 0.f};
    if (e == 0) cnt[0] = 0;
  } else if (bid < 768) {
    int e = ((bid - 512) * 256 + t) * 8;  // W3 -> bf16
    float4 f0 = *(const float4*)(W3 + e);
    float4 f1 = *(const float4*)(W3 + e + 4);
    ushort8 v;
    v[0] = f2bf(f0.x); v[1] = f2bf(f0.y); v[2] = f2bf(f0.z); v[3] = f2bf(f0.w);
    v[4] = f2bf(f1.x); v[5] = f2bf(f1.y); v[6] = f2bf(f1.z); v[7] = f2bf(f1.w);
    *(ushort8*)(W3b + e) = v;
  } else if (bid < 1024) {
    int e = ((bid - 768) * 256 + t) * 8;  // W1 -> hi/lo bf16
    float ff[8];
    *(float4*)&ff[0] = *(const float4*)(W1 + e);
    *(float4*)&ff[4] = *(const float4*)(W1 + e + 4);
    ushort8 h, l;
#pragma unroll
    for (int i = 0; i < 8; i++) {
      unsigned short hi = f2bf(ff[i]);
      h[i] = hi;
      l[i] = f2bf(ff[i] - bf2f(hi));
    }
    *(ushort8*)(w1h + e) = h;
    *(ushort8*)(w1l + e) = l;
  } else {
    int k = bid - 1024;  // const[k]
    float s = 0.f;
    for (int j = t; j < 4096; j += 256) s += W3[k * 4096 + j] * b2[j];
#pragma unroll
    for (int mk = 1; mk < 64; mk <<= 1) s += __shfl_xor(s, mk, 64);
    if ((t & 63) == 0) red[t >> 6] = s;
    __syncthreads();
    if (t == 0) constv[k] = red[0] + red[1] + red[2] + red[3] + b3[k];
  }
}

// ---------------------------------------------------------------------------
// K1 v6 = round-4 proven kernel (352 µs total, passed) + barrier fix:
//   - double-buffered wavebuf -> ONE barrier per seg (was 2)
//   - lgkm-only raw barrier -> global A-frag loads (L2) stay in flight
//     across the barrier instead of being vmcnt(0)-drained every seg.
//   - merge distributed: lane<8 of every wave handles its own 8 rows
//     (was: wave 0 handled all 64 -> per-seg straggler).
// Everything else identical to round 4: 512 blocks x 512 thr, swapped
// operands (A=W1 hi/lo bf16 from L2, B=x fp32->hi/lo bf16 in LDS), 3-term
// MFMA (wh*xh + wl*xh + wh*xl == round-1's accumulation order ->
// bit-identical logits), col-packed quantized keys, MARGIN2 flag criterion,
// separate exact k1_fix.
// Race analysis for 1-barrier/seg: merge of seg s reads buf[s&1] after the
// seg-s barrier; buf[s&1] is rewritten only at seg s+2, which any wave
// reaches only after the seg-(s+1) barrier that the merging lanes must also
// pass -> no WAR.
// ---------------------------------------------------------------------------
__global__ __launch_bounds__(512, 4) void k1_mfma(
    const float* __restrict__ x, const unsigned short* __restrict__ w1h,
    const unsigned short* __restrict__ w1l, const float* __restrict__ b1,
    int* __restrict__ idxbuf, int* __restrict__ cnt, int* __restrict__ list) {
  __shared__ unsigned short xsh[64 * 136];  // stride 136 shorts (proven layout)
  __shared__ unsigned short xsl[64 * 136];
  __shared__ uint2 wavebuf[2][8 * 64];      // double-buffered [wave][row] pairs

  const int t = threadIdx.x;
  const int r0 = blockIdx.x * 64;

  // ---- stage x rows 64x128, hi/lo bf16 split (once per block) ----
#pragma unroll
  for (int it = 0; it < 2; it++) {
    int ch = it * 512 + t;          // 1024 chunks of 8 elems
    int row = ch >> 4, k8 = ch & 15;
    float ff[8];
    *(float4*)&ff[0] = *(const float4*)(x + (r0 + row) * 128 + k8 * 8);
    *(float4*)&ff[4] = *(const float4*)(x + (r0 + row) * 128 + k8 * 8 + 4);
    ushort8 h, l;
#pragma unroll
    for (int i = 0; i < 8; i++) {
      unsigned short hi = f2bf(ff[i]);
      h[i] = hi;
      l[i] = f2bf(ff[i] - bf2f(hi));
    }
    *(ushort8*)&xsh[row * 136 + k8 * 8] = h;
    *(ushort8*)&xsl[row * 136 + k8 * 8] = l;
  }
  __syncthreads();

  const int lane = t & 63, w = t >> 6;      // 8 waves
  const int m = lane & 15, q = lane >> 4;

  for (int seg = 0; seg < 16; ++seg) {
    const int cb = seg * 256 + w * 32;      // wave's first seg-col

    f32x4 acc[2][4];
#pragma unroll
    for (int a = 0; a < 2; a++)
#pragma unroll
      for (int b = 0; b < 4; b++) acc[a][b] = (f32x4){0.f, 0.f, 0.f, 0.f};

#pragma unroll
    for (int ks = 0; ks < 4; ks++) {
      const int k0 = ks * 32;
      // A-frags: W1 hi/lo rows cb+a*16+m (global, L2-resident)
      bf16x8 ah[2], al[2];
#pragma unroll
      for (int a = 0; a < 2; a++) {
        const size_t woff = (size_t)(cb + a * 16 + m) * 128 + k0 + q * 8;
        ah[a] = *(const bf16x8*)(w1h + woff);
        al[a] = *(const bf16x8*)(w1l + woff);
      }
      // B-frags: x rows from LDS (hi/lo)
#pragma unroll
      for (int bp = 0; bp < 2; bp++) {
        bf16x8 bh[2], bl[2];
#pragma unroll
        for (int bb = 0; bb < 2; bb++) {
          const int roff = ((bp * 2 + bb) * 16 + m) * 136 + k0 + q * 8;
          bh[bb] = *(const bf16x8*)&xsh[roff];
          bl[bb] = *(const bf16x8*)&xsl[roff];
        }
#pragma unroll
        for (int a = 0; a < 2; a++)
#pragma unroll
          for (int bb = 0; bb < 2; bb++) {
            const int b = bp * 2 + bb;
            acc[a][b] = __builtin_amdgcn_mfma_f32_16x16x32_bf16(ah[a], bh[bb], acc[a][b], 0, 0, 0);
            acc[a][b] = __builtin_amdgcn_mfma_f32_16x16x32_bf16(al[a], bh[bb], acc[a][b], 0, 0, 0);
            acc[a][b] = __builtin_amdgcn_mfma_f32_16x16x32_bf16(ah[a], bl[bb], acc[a][b], 0, 0, 0);
          }
      }
    }

    // ---- epilogue: per-row top-2 keys (round-4 proven math) ----
    float4 bias4[2];
#pragma unroll
    for (int a = 0; a < 2; a++)
      bias4[a] = *(const float4*)&b1[cb + a * 16 + q * 4];

#pragma unroll
    for (int b = 0; b < 4; b++) {
      unsigned int K1 = 0u, K2 = 0u;
#pragma unroll
      for (int a = 0; a < 2; a++)
#pragma unroll
        for (int r = 0; r < 4; r++) {
          float v = acc[a][b][r] + bias4[a][r];
          unsigned int col = (unsigned)(w * 32 + a * 16 + q * 4 + r);
          unsigned int key = (f2ord(v) & 0xFFFFFF00u) | (255u - col);
          unsigned int mx = K1 > key ? K1 : key;
          unsigned int mn = K1 > key ? key : K1;
          K1 = mx; K2 = K2 > mn ? K2 : mn;
        }
#pragma unroll
      for (int msk = 16; msk <= 32; msk <<= 1) {
        unsigned int p1 = (unsigned int)__shfl_xor((int)K1, msk, 64);
        unsigned int p2 = (unsigned int)__shfl_xor((int)K2, msk, 64);
        unsigned int mx = K1 > p1 ? K1 : p1;
        unsigned int mn = K1 > p1 ? p1 : K1;
        unsigned int sel = K1 >= p1 ? K2 : p2;
        K1 = mx;
        K2 = sel > mn ? sel : mn;
      }
      if (lane < 16) {  // q == 0
        uint2 pr; pr.x = K1; pr.y = K2;
        wavebuf[seg & 1][w * 64 + b * 16 + m] = pr;
      }
    }

    barrier_lgkm();  // wavebuf[seg&1] writes visible; globals stay in flight

    // ---- distributed merge: lane<8 of wave w handles rows w*8..w*8+7 ----
    if (lane < 8) {
      const int row = w * 8 + lane;
      unsigned int K1 = 0u, K2 = 0u;
#pragma unroll
      for (int wp = 0; wp < 8; wp++) {
        uint2 pr = wavebuf[seg & 1][wp * 64 + row];
        unsigned int mx = K1 > pr.x ? K1 : pr.x;
        unsigned int mn = K1 > pr.x ? pr.x : K1;
        unsigned int sel = K1 >= pr.x ? K2 : pr.y;
        K1 = mx;
        K2 = sel > mn ? sel : mn;
      }
      int colw = 255 - (int)(K1 & 255u);
      int bgl = r0 + row;
      idxbuf[bgl * 16 + seg] = colw;
      float v1 = ord2f(K1 & 0xFFFFFF00u);
      float v2 = ord2f(K2 & 0xFFFFFF00u);
      if (v1 - v2 < MARGIN2) {
        int p = atomicAdd(cnt, 1);
        if (p < FIX_CAP) list[p] = (bgl << 4) | seg;
      }
    }
    // no second barrier: next seg writes wavebuf[(seg+1)&1] (other buffer)
  }
}

// ---------------------------------------------------------------------------
// K1fix: exact fp32 recompute for flagged (b,seg) — proven numerics
// (ascending-k fmaf from b1[c], lowest-index argmax tie-break).
// ---------------------------------------------------------------------------
__global__ __launch_bounds__(256) void k1_fix(
    const float* __restrict__ x, const float* __restrict__ W1,
    const float* __restrict__ b1, const int* __restrict__ cnt,
    const int* __restrict__ list, int* __restrict__ idxbuf) {
  __shared__ float redv[4];
  __shared__ int   redi[4];
  const int t = threadIdx.x;
  const int lane = t & 63, wv = t >> 6;
  int n = cnt[0]; if (n > FIX_CAP) n = FIX_CAP;
  for (int e = blockIdx.x; e < n; e += gridDim.x) {
    int pk = list[e];
    int b = pk >> 4, seg = pk & 15;
    int c = seg * 256 + t;
    float a = b1[c];
    const float4* xr = (const float4*)(x + (size_t)b * 128);
    const float4* wr = (const float4*)(W1 + (size_t)c * 128);
#pragma unroll 8
    for (int k4 = 0; k4 < 32; k4++) {
      float4 xv = xr[k4];
      float4 wv4 = wr[k4];
      a = fmaf(xv.x, wv4.x, a);
      a = fmaf(xv.y, wv4.y, a);
      a = fmaf(xv.z, wv4.z, a);
      a = fmaf(xv.w, wv4.w, a);
    }
    float v = a; int li = t;
#pragma unroll
    for (int msk = 1; msk < 64; msk <<= 1) {
      float u = __shfl_xor(v, msk, 64);
      int ju = __shfl_xor(li, msk, 64);
      if (u > v || (u == v && ju < li)) { v = u; li = ju; }
    }
    if (lane == 0) { redv[wv] = v; redi[wv] = li; }
    __syncthreads();
    if (t == 0) {
      float bv = redv[0]; int bi = redi[0];
#pragma unroll
      for (int w = 1; w < 4; w++) {
        if (redv[w] > bv || (redv[w] == bv && redi[w] < bi)) { bv = redv[w]; bi = redi[w]; }
      }
      idxbuf[b * 16 + seg] = bi;
    }
    __syncthreads();
  }
}

// ---------------------------------------------------------------------------
// K2 v6: Mt[c,k] += sum_j W2[j,c]*W3[k,j], splitK=8, LDS-transposed staging
// (round-4 proven) + register prefetch of next iter's W2 float4s issued
// before the MFMA phase (HBM latency hides under MFMA + W3b L2 reads) +
// lgkm-only barriers (prefetch loads stay in flight across them).
// MFMA inputs bit-identical to round 4.
// ---------------------------------------------------------------------------
__global__ __launch_bounds__(256) void k2_mfma(const float* __restrict__ W2,
                                               const unsigned short* __restrict__ W3b,
                                               float* __restrict__ Mt) {
  __shared__ unsigned short ldsT[64 * 40];
  const int t = threadIdx.x;
  const int lane = t & 63, wv = t >> 6;
  const int c0 = blockIdx.x * 64;
  const int jq = blockIdx.y;
  const int m = lane & 15, q = lane >> 4;
  const int jl0 = t >> 4, cq0 = t & 15;            // fid = t
  const int jl1 = (256 + t) >> 4, cq1 = t & 15;    // fid = 256 + t
  f32x4 acc[8];
#pragma unroll
  for (int nt = 0; nt < 8; nt++) acc[nt] = (f32x4){0.f, 0.f, 0.f, 0.f};

  // preload it=0
  float4 p0 = *(const float4*)&W2[(size_t)(jq * 512 + jl0) * 4096 + c0 + cq0 * 4];
  float4 p1 = *(const float4*)&W2[(size_t)(jq * 512 + jl1) * 4096 + c0 + cq1 * 4];

  for (int it = 0; it < 16; it++) {
    const int j0 = jq * 512 + it * 32;
    // stage regs -> LDS (transposed, f32->bf16)
    ldsT[(cq0 * 4 + 0) * 40 + jl0] = f2bf(p0.x);
    ldsT[(cq0 * 4 + 1) * 40 + jl0] = f2bf(p0.y);
    ldsT[(cq0 * 4 + 2) * 40 + jl0] = f2bf(p0.z);
    ldsT[(cq0 * 4 + 3) * 40 + jl0] = f2bf(p0.w);
    ldsT[(cq1 * 4 + 0) * 40 + jl1] = f2bf(p1.x);
    ldsT[(cq1 * 4 + 1) * 40 + jl1] = f2bf(p1.y);
    ldsT[(cq1 * 4 + 2) * 40 + jl1] = f2bf(p1.z);
    ldsT[(cq1 * 4 + 3) * 40 + jl1] = f2bf(p1.w);
    barrier_lgkm();
    bf16x8 av = *(const bf16x8*)&ldsT[(wv * 16 + m) * 40 + q * 8];
    // prefetch next iter while MFMA phase runs
    if (it + 1 < 16) {
      const int jn = j0 + 32;
      p0 = *(const float4*)&W2[(size_t)(jn + jl0) * 4096 + c0 + cq0 * 4];
      p1 = *(const float4*)&W2[(size_t)(jn + jl1) * 4096 + c0 + cq1 * 4];
    }
#pragma unroll
    for (int nt = 0; nt < 8; nt++) {
      bf16x8 b = *(const bf16x8*)(W3b + (nt * 16 + m) * 4096 + j0 + q * 8);
      acc[nt] = __builtin_amdgcn_mfma_f32_16x16x32_bf16(av, b, acc[nt], 0, 0, 0);
    }
    barrier_lgkm();  // av reads drained; ldsT safe to overwrite next iter
  }
#pragma unroll
  for (int nt = 0; nt < 8; nt++)
#pragma unroll
    for (int r = 0; r < 4; r++)
      atomicAdd(&Mt[(size_t)(c0 + wv * 16 + q * 4 + r) * 128 + nt * 16 + m], acc[nt][r]);
}

// ---------------------------------------------------------------------------
// K3: out[b,k] = const[k] + sum_g Mt[g*256 + idx[b,g], k]  (unchanged)
// ---------------------------------------------------------------------------
__global__ __launch_bounds__(256) void k3_gather(const int* __restrict__ idxbuf,
                                                 const float* __restrict__ Mt,
                                                 const float* __restrict__ constv,
                                                 float* __restrict__ out) {
  const int t = threadIdx.x;
  const int w = t >> 6;
  const int lane = t & 63;
  const int b = blockIdx.x * 4 + w;
  float a0 = constv[lane];
  float a1 = constv[lane + 64];
  const int* ib = idxbuf + b * 16;
  int cg[16];
#pragma unroll
  for (int g = 0; g < 16; g++) cg[g] = g * 256 + ib[g];
#pragma unroll
  for (int g = 0; g < 16; g++) {
    const float* mrow = Mt + (size_t)cg[g] * 128;
    a0 += mrow[lane];
    a1 += mrow[lane + 64];
  }
  out[b * 128 + lane] = a0;
  out[b * 128 + lane + 64] = a1;
}

// ---------------------------------------------------------------------------
extern "C" void kernel_launch(void* const* d_in, const int* in_sizes, int n_in,
                              void* d_out, int out_size, void* d_ws, size_t ws_size,
                              hipStream_t stream) {
  const float* x  = (const float*)d_in[0];
  const float* W1 = (const float*)d_in[1];
  const float* b1 = (const float*)d_in[2];
  const float* W2 = (const float*)d_in[3];
  const float* b2 = (const float*)d_in[4];
  const float* W3 = (const float*)d_in[5];
  const float* b3 = (const float*)d_in[6];
  float* out = (float*)d_out;

  char* w = (char*)d_ws;
  int* idxbuf         = (int*)(w);                           // 2 MB
  unsigned short* W3b = (unsigned short*)(w + (2u << 20));   // 1 MB
  float* Mt           = (float*)(w + (3u << 20));            // 2 MB
  unsigned short* w1h = (unsigned short*)(w + (5u << 20));   // 1 MB (bf16 hi)
  unsigned short* w1l = (unsigned short*)(w + (6u << 20));   // 1 MB (bf16 lo)
  float* constv       = (float*)(w + (7u << 20));            // 512 B
  int* cnt            = (int*)(w + (7u << 20) + 1024);       // 4 B
  int* fixlist        = (int*)(w + (7u << 20) + 4096);       // 256 KB

  kprep<<<1152, 256, 0, stream>>>(Mt, cnt, W3, W3b, W1, w1h, w1l, b2, b3, constv);
  k1_mfma<<<512, 512, 0, stream>>>(x, w1h, w1l, b1, idxbuf, cnt, fixlist);
  k1_fix<<<1024, 256, 0, stream>>>(x, W1, b1, cnt, fixlist, idxbuf);
  k2_mfma<<<dim3(64, 8), 256, 0, stream>>>(W2, W3b, Mt);
  k3_gather<<<8192, 256, 0, stream>>>(idxbuf, Mt, constv, out);
}